// Round 3
// baseline (6083.556 us; speedup 1.0000x reference)
//
#include <hip/hip_runtime.h>
#include <hip/hip_bf16.h>

#define D_DIM 256
#define R_REL 8
#define MAXC 256

typedef __attribute__((ext_vector_type(8))) short short8;
typedef __attribute__((ext_vector_type(4))) float f32x4;

static __device__ __forceinline__ unsigned short f2bf(float f) {
  unsigned u = __float_as_uint(f);
  u += 0x7FFF + ((u >> 16) & 1);   // round-to-nearest-even
  return (unsigned short)(u >> 16);
}

// ---- weight prep -----------------------------------------------------------

// Bt[n][k] = (k < 2048 ? W[k/256][k%256][n] : root[k-2048][n]), bf16, k-contiguous
__global__ void k_build_bt(const float* __restrict__ w, const float* __restrict__ root,
                           unsigned short* __restrict__ bt) {
  const int KT = R_REL * D_DIM + D_DIM;  // 2304
  int idx = blockIdx.x * 256 + threadIdx.x;
  if (idx >= D_DIM * KT) return;
  int n = idx / KT, k = idx - n * KT;
  float v = (k < R_REL * D_DIM) ? w[(size_t)k * D_DIM + n]
                                : root[(size_t)(k - R_REL * D_DIM) * D_DIM + n];
  bt[idx] = f2bf(v);
}

__global__ void k_cvt_bf16(const float* __restrict__ in, unsigned short* __restrict__ out,
                           int n4) {
  int i = blockIdx.x * 256 + threadIdx.x;
  if (i >= n4) return;
  float4 v = ((const float4*)in)[i];
  ushort4 o = { f2bf(v.x), f2bf(v.y), f2bf(v.z), f2bf(v.w) };
  ((ushort4*)out)[i] = o;
}

// ---- edge bucketing by dst-chunk -------------------------------------------

__global__ void k_hist(const int* __restrict__ dst, int* __restrict__ hcnt,
                       int E, int Nc) {
  int i = blockIdx.x * 256 + threadIdx.x;
  if (i < E) atomicAdd(&hcnt[dst[i] / Nc], 1);
}

__global__ void k_scan(const int* __restrict__ hcnt, int* __restrict__ offs,
                       int* __restrict__ cur, int nchunks) {
  if (blockIdx.x == 0 && threadIdx.x == 0) {
    int acc = 0;
    for (int c = 0; c < nchunks; ++c) { offs[c] = acc; cur[c] = acc; acc += hcnt[c]; }
    offs[nchunks] = acc;
  }
}

__global__ void k_place(const int* __restrict__ src, const int* __restrict__ dst,
                        const int* __restrict__ et, int* __restrict__ cur,
                        int* __restrict__ seg_s, int* __restrict__ src_s,
                        int E, int Nc) {
  int i = blockIdx.x * 256 + threadIdx.x;
  if (i >= E) return;
  int d = dst[i];
  int p = atomicAdd(&cur[d / Nc], 1);
  seg_s[p] = d * R_REL + et[i];
  src_s[p] = src[i];
}

// ---- per-chunk aggregation -------------------------------------------------

__global__ void k_aggregate(const float* __restrict__ xsrc,
                            const int* __restrict__ seg_s, const int* __restrict__ src_s,
                            const int* __restrict__ offs, int c, int n0,
                            float* __restrict__ sums, int* __restrict__ cnt) {
  int lo = offs[c], hi = offs[c + 1];
  int wid = (blockIdx.x * 256 + threadIdx.x) >> 6;
  int lane = threadIdx.x & 63;
  int nw = (gridDim.x * 256) >> 6;
  for (int i = lo + wid; i < hi; i += nw) {
    int seg = seg_s[i] - n0 * R_REL;
    int s = src_s[i];
    if (lane == 0) atomicAdd(&cnt[seg], 1);
    float4 v = ((const float4*)(xsrc + (size_t)s * D_DIM))[lane];
    float* o = sums + (size_t)seg * D_DIM + lane * 4;
    atomicAdd(o + 0, v.x);
    atomicAdd(o + 1, v.y);
    atomicAdd(o + 2, v.z);
    atomicAdd(o + 3, v.w);
  }
}

// In-place: segment slot sg holds 256 fp32 (1024 B); after this kernel the
// first 512 B hold the 256 bf16 mean values. One wave owns one slot; its load
// precedes its store in program order, so the overlap is race-free.
__global__ void k_finalize(float* __restrict__ sums, const int* __restrict__ cnt,
                           int nseg) {
  int sg = blockIdx.x * 4 + (threadIdx.x >> 6);
  if (sg >= nseg) return;
  int lane = threadIdx.x & 63;
  float inv = 1.0f / fmaxf((float)cnt[sg], 1.0f);
  float4 v = ((const float4*)(sums + (size_t)sg * D_DIM))[lane];
  ushort4 o = { f2bf(v.x * inv), f2bf(v.y * inv), f2bf(v.z * inv), f2bf(v.w * inv) };
  ((ushort4*)((unsigned short*)sums + (size_t)sg * 512))[lane] = o;
}

// ---- GEMM ------------------------------------------------------------------
// C(Mc x 256) = [Agg (Mc x 2048, slot layout n*4096 + r*512 + d) | Aroot (Mc x 256)]
//               @ Bt^T (+bias, opt relu). 128x128 tile, BK=64, 4 waves (2x2),
// 16x16x32 bf16 MFMA. LDS [128][64 bf16] XOR-swizzled: 16B-element c16 of row r
// lives at slot (c16 ^ (r&7)); LDS dest stays linear-in-lane (m104), the GLOBAL
// source is inverse-swizzled (m173), the ds_read applies the same XOR (rule 21).

__device__ __forceinline__ void gload_lds16(const void* g, void* l) {
  __builtin_amdgcn_global_load_lds(
      (const __attribute__((address_space(1))) void*)g,
      (__attribute__((address_space(3))) void*)l, 16, 0, 0);
}

template <int RELU_BF16>
__global__ __launch_bounds__(256, 2) void k_gemm(
    const unsigned short* __restrict__ Agg,    // node n, rel r, col d at n*4096+r*512+d
    const unsigned short* __restrict__ Aroot,  // Mc x 256 contiguous
    const unsigned short* __restrict__ Bt,     // 256 x 2304
    const float* __restrict__ bias,            // 256
    void* __restrict__ Cout,                   // Mc x 256 (bf16 if RELU_BF16 else f32)
    int M) {
  const int KT = 2304, KA = 2048;
  __shared__ __align__(16) char smA[128 * 128];
  __shared__ __align__(16) char smB[128 * 128];
  int tid = threadIdx.x;
  int bn = blockIdx.x & 1;
  int bm = blockIdx.x >> 1;
  int lane = tid & 63;
  int wv = tid >> 6, wm = wv >> 1, wn = wv & 1;
  int lr = lane & 15, lk = lane >> 4;

  f32x4 acc[4][4] = {};

  int rloc = tid >> 3;     // 0..31 (+ c*32)
  int sslot = tid & 7;     // 16B slot within a 128B LDS row

  for (int step = 0; step < KT / 64; ++step) {
    int k0 = step * 64;
    const unsigned short* Ap;
    int strideA, colA;
    if (k0 < KA) { Ap = Agg + (size_t)(k0 >> 8) * 512; strideA = 4096; colA = k0 & 255; }
    else         { Ap = Aroot;                         strideA = 256;  colA = k0 - KA; }

    __syncthreads();
#pragma unroll
    for (int c = 0; c < 4; ++c) {
      int r = c * 32 + rloc;
      int c16 = sslot ^ (r & 7);                 // inverse-swizzled source element
      int gr = bm * 128 + r; if (gr >= M) gr = M - 1;
      gload_lds16(Ap + (size_t)gr * strideA + colA + c16 * 8,
                  smA + r * 128 + sslot * 16);
      gload_lds16(Bt + (size_t)(bn * 128 + r) * KT + k0 + c16 * 8,
                  smB + r * 128 + sslot * 16);
    }
    asm volatile("s_waitcnt vmcnt(0)" ::: "memory");
    __syncthreads();

#pragma unroll
    for (int ks = 0; ks < 2; ++ks) {
      short8 af[4], bfr[4];
#pragma unroll
      for (int m = 0; m < 4; ++m) {
        int row = wm * 64 + m * 16 + lr;
        af[m] = *(const short8*)(smA + row * 128 + (((ks * 4 + lk) ^ (row & 7)) << 4));
      }
#pragma unroll
      for (int n = 0; n < 4; ++n) {
        int row = wn * 64 + n * 16 + lr;
        bfr[n] = *(const short8*)(smB + row * 128 + (((ks * 4 + lk) ^ (row & 7)) << 4));
      }
#pragma unroll
      for (int m = 0; m < 4; ++m)
#pragma unroll
        for (int n = 0; n < 4; ++n)
          acc[m][n] = __builtin_amdgcn_mfma_f32_16x16x32_bf16(af[m], bfr[n], acc[m][n], 0, 0, 0);
    }
  }

  // epilogue: C/D layout col=lane&15, row=(lane>>4)*4+reg (m89)
#pragma unroll
  for (int n = 0; n < 4; ++n) {
    int col = bn * 128 + wn * 64 + n * 16 + lr;
    float bv = bias[col];
#pragma unroll
    for (int m = 0; m < 4; ++m) {
#pragma unroll
      for (int j = 0; j < 4; ++j) {
        int row = bm * 128 + wm * 64 + m * 16 + lk * 4 + j;
        if (row < M) {
          float v = acc[m][n][j] + bv;
          if (RELU_BF16) {
            v = fmaxf(v, 0.0f);
            ((unsigned short*)Cout)[(size_t)row * D_DIM + col] = f2bf(v);
          } else {
            ((float*)Cout)[(size_t)row * D_DIM + col] = v;
          }
        }
      }
    }
  }
}

// ---- launch ----------------------------------------------------------------

extern "C" void kernel_launch(void* const* d_in, const int* in_sizes, int n_in,
                              void* d_out, int out_size, void* d_ws, size_t ws_size,
                              hipStream_t stream) {
  const float* x_src = (const float*)d_in[0];
  const float* x_dst = (const float*)d_in[1];
  const int*   eidx  = (const int*)d_in[2];
  const int*   etype = (const int*)d_in[3];
  const float* w1    = (const float*)d_in[4];
  const float* root1 = (const float*)d_in[5];
  const float* b1    = (const float*)d_in[6];
  const float* w2    = (const float*)d_in[7];
  const float* root2 = (const float*)d_in[8];
  const float* b2    = (const float*)d_in[9];

  const int E  = in_sizes[3];
  const int Nd = in_sizes[1] / D_DIM;
  const int* srcI = eidx;
  const int* dstI = eidx + E;

  char* ws = (char*)d_ws;
  size_t off = 0;
  auto alloc = [&](size_t bytes) {
    size_t o = off;
    off += (bytes + 255) & ~(size_t)255;
    return o;
  };
  // fixed region
  size_t o_bt1  = alloc((size_t)D_DIM * 2304 * 2);
  size_t o_bt2  = alloc((size_t)D_DIM * 2304 * 2);
  size_t o_xd   = alloc((size_t)Nd * D_DIM * 2);
  size_t o_seg  = alloc((size_t)E * 4);
  size_t o_src  = alloc((size_t)E * 4);
  size_t o_hcnt = alloc((size_t)MAXC * 4);
  size_t o_offs = alloc((size_t)(MAXC + 1) * 4);
  size_t o_cur  = alloc((size_t)MAXC * 4);
  size_t fixed_end = off;

  // adaptive chunk size: per-node = cnt(32) + sums(8192) + h(512)
  const size_t per_node = 8 * 4 + 8 * 1024 + 512;
  long long avail = (long long)ws_size - (long long)fixed_end - 4096;
  int Nc = avail > 0 ? (int)(avail / (long long)per_node) : 0;
  if (Nc > Nd) Nc = Nd;
  Nc = (Nc / 128) * 128;
  if (Nc < 128) {  // hopelessly small ws: deterministic zero output (diagnostic)
    hipMemsetAsync(d_out, 0, (size_t)out_size * 4, stream);
    return;
  }
  int nchunks = (Nd + Nc - 1) / Nc;
  int NcB = (((Nd + nchunks - 1) / nchunks) + 127) / 128 * 128;  // balance chunks
  if (NcB <= Nc) Nc = NcB;
  nchunks = (Nd + Nc - 1) / Nc;

  unsigned short* bt1  = (unsigned short*)(ws + o_bt1);
  unsigned short* bt2  = (unsigned short*)(ws + o_bt2);
  unsigned short* xd16 = (unsigned short*)(ws + o_xd);
  int* seg_s = (int*)(ws + o_seg);
  int* src_s = (int*)(ws + o_src);
  int* hcnt  = (int*)(ws + o_hcnt);
  int* offs  = (int*)(ws + o_offs);
  int* cur   = (int*)(ws + o_cur);

  char* chunk_base = ws + fixed_end;
  int*   cnt_c  = (int*)chunk_base;                                   // Nc*8 ints
  float* sums_c = (float*)(chunk_base + (size_t)Nc * 32);             // Nc*8*1024 B
  unsigned short* agg_c = (unsigned short*)sums_c;                    // bf16 in place
  unsigned short* h_c   = (unsigned short*)(chunk_base + (size_t)Nc * 32 +
                                            (size_t)Nc * 8192);       // Nc*512 B

  // ---- fixed prep ----
  hipMemsetAsync(hcnt, 0, MAXC * 4, stream);
  k_build_bt<<<(D_DIM * 2304 + 255) / 256, 256, 0, stream>>>(w1, root1, bt1);
  k_build_bt<<<(D_DIM * 2304 + 255) / 256, 256, 0, stream>>>(w2, root2, bt2);
  k_cvt_bf16<<<(Nd * 64 + 255) / 256, 256, 0, stream>>>(x_dst, xd16, Nd * 64);
  k_hist<<<(E + 255) / 256, 256, 0, stream>>>(dstI, hcnt, E, Nc);
  k_scan<<<1, 64, 0, stream>>>(hcnt, offs, cur, nchunks);
  k_place<<<(E + 255) / 256, 256, 0, stream>>>(srcI, dstI, etype, cur, seg_s, src_s, E, Nc);

  // ---- chunk loop ----
  for (int c = 0; c < nchunks; ++c) {
    int n0 = c * Nc;
    int Mc = Nd - n0 < Nc ? Nd - n0 : Nc;
    hipMemsetAsync(cnt_c, 0, (size_t)Mc * 32, stream);
    hipMemsetAsync(sums_c, 0, (size_t)Mc * 8192, stream);
    k_aggregate<<<512, 256, 0, stream>>>(x_src, seg_s, src_s, offs, c, n0, sums_c, cnt_c);
    k_finalize<<<(Mc * 8 + 3) / 4, 256, 0, stream>>>(sums_c, cnt_c, Mc * 8);
    int mb = (Mc + 127) / 128;
    k_gemm<1><<<mb * 2, 256, 0, stream>>>(agg_c, xd16 + (size_t)n0 * D_DIM, bt1, b1,
                                          (void*)h_c, Mc);
    k_gemm<0><<<mb * 2, 256, 0, stream>>>(agg_c, h_c, bt2, b2,
                                          (void*)((float*)d_out + (size_t)n0 * D_DIM), Mc);
  }
}

// Round 4
// 1431.266 us; speedup vs baseline: 4.2505x; 4.2505x over previous
//
#include <hip/hip_runtime.h>
#include <hip/hip_bf16.h>

#define D_DIM 256
#define R_REL 8

typedef __attribute__((ext_vector_type(8))) short short8;
typedef __attribute__((ext_vector_type(4))) float f32x4;

static __device__ __forceinline__ unsigned short f2bf(float f) {
  unsigned u = __float_as_uint(f);
  u += 0x7FFF + ((u >> 16) & 1);   // round-to-nearest-even
  return (unsigned short)(u >> 16);
}

// ---- weight prep -----------------------------------------------------------

// Bt[n][k] = (k < 2048 ? W[k/256][k%256][n] : root[k-2048][n]), bf16, k-contiguous
__global__ void k_build_bt(const float* __restrict__ w, const float* __restrict__ root,
                           unsigned short* __restrict__ bt) {
  const int KT = R_REL * D_DIM + D_DIM;  // 2304
  int idx = blockIdx.x * 256 + threadIdx.x;
  if (idx >= D_DIM * KT) return;
  int n = idx / KT, k = idx - n * KT;
  float v = (k < R_REL * D_DIM) ? w[(size_t)k * D_DIM + n]
                                : root[(size_t)(k - R_REL * D_DIM) * D_DIM + n];
  bt[idx] = f2bf(v);
}

__global__ void k_cvt_bf16(const float* __restrict__ in, unsigned short* __restrict__ out,
                           int n4) {
  int i = blockIdx.x * 256 + threadIdx.x;
  if (i >= n4) return;
  float4 v = ((const float4*)in)[i];
  ushort4 o = { f2bf(v.x), f2bf(v.y), f2bf(v.z), f2bf(v.w) };
  ((ushort4*)out)[i] = o;
}

// ---- per-chunk aggregation (full edge scan, range filter) ------------------

__global__ void k_aggregate(const float* __restrict__ xsrc,
                            const int* __restrict__ src, const int* __restrict__ dst,
                            const int* __restrict__ et, int n0, int n1,
                            float* __restrict__ sums, int* __restrict__ cnt, int E) {
  int wid = (blockIdx.x * 256 + threadIdx.x) >> 6;
  int lane = threadIdx.x & 63;
  int nw = (gridDim.x * 256) >> 6;
  for (int i = wid; i < E; i += nw) {
    int d = dst[i];
    if (d < n0 || d >= n1) continue;
    int seg = (d - n0) * R_REL + et[i];
    int s = src[i];
    if (lane == 0) atomicAdd(&cnt[seg], 1);
    float4 v = ((const float4*)(xsrc + (size_t)s * D_DIM))[lane];
    float* o = sums + (size_t)seg * D_DIM + lane * 4;
    atomicAdd(o + 0, v.x);
    atomicAdd(o + 1, v.y);
    atomicAdd(o + 2, v.z);
    atomicAdd(o + 3, v.w);
  }
}

// In-place: segment slot sg holds 256 fp32 (1024 B); after this kernel the
// first 512 B hold the 256 bf16 mean values. One wave owns one slot; its load
// precedes its store in program order, so the overlap is race-free.
__global__ void k_finalize(float* __restrict__ sums, const int* __restrict__ cnt,
                           int nseg) {
  int sg = blockIdx.x * 4 + (threadIdx.x >> 6);
  if (sg >= nseg) return;
  int lane = threadIdx.x & 63;
  float inv = 1.0f / fmaxf((float)cnt[sg], 1.0f);
  float4 v = ((const float4*)(sums + (size_t)sg * D_DIM))[lane];
  ushort4 o = { f2bf(v.x * inv), f2bf(v.y * inv), f2bf(v.z * inv), f2bf(v.w * inv) };
  ((ushort4*)((unsigned short*)sums + (size_t)sg * 512))[lane] = o;
}

// ---- GEMM ------------------------------------------------------------------
// C(Mc x 256) = [Agg (Mc x 2048, slot layout n*4096 + r*512 + d) | Aroot (Mc x 256)]
//               @ Bt^T (+bias, opt relu). 128x128 tile, BK=64, 4 waves (2x2),
// 16x16x32 bf16 MFMA. LDS [128][64 bf16] XOR-swizzled: 16B-element c16 of row r
// lives at slot (c16 ^ (r&7)); LDS dest stays linear-in-lane (m104), the GLOBAL
// source is inverse-swizzled (m173), the ds_read applies the same XOR (rule 21).

__device__ __forceinline__ void gload_lds16(const void* g, void* l) {
  __builtin_amdgcn_global_load_lds(
      (const __attribute__((address_space(1))) void*)g,
      (__attribute__((address_space(3))) void*)l, 16, 0, 0);
}

template <int RELU_BF16>
__global__ __launch_bounds__(256, 2) void k_gemm(
    const unsigned short* __restrict__ Agg,    // node n, rel r, col d at n*4096+r*512+d
    const unsigned short* __restrict__ Aroot,  // Mc x 256 contiguous
    const unsigned short* __restrict__ Bt,     // 256 x 2304
    const float* __restrict__ bias,            // 256
    void* __restrict__ Cout,                   // Mc x 256 (bf16 if RELU_BF16 else f32)
    int M) {
  const int KT = 2304, KA = 2048;
  __shared__ __align__(16) char smA[128 * 128];
  __shared__ __align__(16) char smB[128 * 128];
  int tid = threadIdx.x;
  int bn = blockIdx.x & 1;
  int bm = blockIdx.x >> 1;
  int lane = tid & 63;
  int wv = tid >> 6, wm = wv >> 1, wn = wv & 1;
  int lr = lane & 15, lk = lane >> 4;

  f32x4 acc[4][4] = {};

  int rloc = tid >> 3;     // 0..31 (+ c*32)
  int sslot = tid & 7;     // 16B slot within a 128B LDS row

  for (int step = 0; step < KT / 64; ++step) {
    int k0 = step * 64;
    const unsigned short* Ap;
    int strideA, colA;
    if (k0 < KA) { Ap = Agg + (size_t)(k0 >> 8) * 512; strideA = 4096; colA = k0 & 255; }
    else         { Ap = Aroot;                         strideA = 256;  colA = k0 - KA; }

    __syncthreads();
#pragma unroll
    for (int c = 0; c < 4; ++c) {
      int r = c * 32 + rloc;
      int c16 = sslot ^ (r & 7);                 // inverse-swizzled source element
      int gr = bm * 128 + r; if (gr >= M) gr = M - 1;
      gload_lds16(Ap + (size_t)gr * strideA + colA + c16 * 8,
                  smA + r * 128 + sslot * 16);
      gload_lds16(Bt + (size_t)(bn * 128 + r) * KT + k0 + c16 * 8,
                  smB + r * 128 + sslot * 16);
    }
    asm volatile("s_waitcnt vmcnt(0)" ::: "memory");
    __syncthreads();

#pragma unroll
    for (int ks = 0; ks < 2; ++ks) {
      short8 af[4], bfr[4];
#pragma unroll
      for (int m = 0; m < 4; ++m) {
        int row = wm * 64 + m * 16 + lr;
        af[m] = *(const short8*)(smA + row * 128 + (((ks * 4 + lk) ^ (row & 7)) << 4));
      }
#pragma unroll
      for (int n = 0; n < 4; ++n) {
        int row = wn * 64 + n * 16 + lr;
        bfr[n] = *(const short8*)(smB + row * 128 + (((ks * 4 + lk) ^ (row & 7)) << 4));
      }
#pragma unroll
      for (int m = 0; m < 4; ++m)
#pragma unroll
        for (int n = 0; n < 4; ++n)
          acc[m][n] = __builtin_amdgcn_mfma_f32_16x16x32_bf16(af[m], bfr[n], acc[m][n], 0, 0, 0);
    }
  }

  // epilogue: C/D layout col=lane&15, row=(lane>>4)*4+reg (m89)
#pragma unroll
  for (int n = 0; n < 4; ++n) {
    int col = bn * 128 + wn * 64 + n * 16 + lr;
    float bv = bias[col];
#pragma unroll
    for (int m = 0; m < 4; ++m) {
#pragma unroll
      for (int j = 0; j < 4; ++j) {
        int row = bm * 128 + wm * 64 + m * 16 + lk * 4 + j;
        if (row < M) {
          float v = acc[m][n][j] + bv;
          if (RELU_BF16) {
            v = fmaxf(v, 0.0f);
            ((unsigned short*)Cout)[(size_t)row * D_DIM + col] = f2bf(v);
          } else {
            ((float*)Cout)[(size_t)row * D_DIM + col] = v;
          }
        }
      }
    }
  }
}

// ---- launch ----------------------------------------------------------------

extern "C" void kernel_launch(void* const* d_in, const int* in_sizes, int n_in,
                              void* d_out, int out_size, void* d_ws, size_t ws_size,
                              hipStream_t stream) {
  const float* x_src = (const float*)d_in[0];
  const float* x_dst = (const float*)d_in[1];
  const int*   eidx  = (const int*)d_in[2];
  const int*   etype = (const int*)d_in[3];
  const float* w1    = (const float*)d_in[4];
  const float* root1 = (const float*)d_in[5];
  const float* b1    = (const float*)d_in[6];
  const float* w2    = (const float*)d_in[7];
  const float* root2 = (const float*)d_in[8];
  const float* b2    = (const float*)d_in[9];

  const int E  = in_sizes[3];
  const int Nd = in_sizes[1] / D_DIM;
  const int* srcI = eidx;
  const int* dstI = eidx + E;

  char* ws = (char*)d_ws;
  size_t off = 0;
  auto alloc = [&](size_t bytes) {
    size_t o = off;
    off += (bytes + 255) & ~(size_t)255;
    return o;
  };
  // fixed region
  size_t o_bt1 = alloc((size_t)D_DIM * 2304 * 2);
  size_t o_bt2 = alloc((size_t)D_DIM * 2304 * 2);
  size_t o_xd  = alloc((size_t)Nd * D_DIM * 2);
  size_t fixed_end = off;

  // adaptive chunk size: per-node = cnt(32) + sums(8192) + h(512)
  const size_t per_node = 8 * 4 + 8 * 1024 + 512;
  long long avail = (long long)ws_size - (long long)fixed_end - 4096;
  int Nc = avail > 0 ? (int)(avail / (long long)per_node) : 0;
  if (Nc > Nd) Nc = Nd;
  Nc = (Nc / 128) * 128;
  if (Nc < 128) {  // hopelessly small ws: deterministic zero output (diagnostic)
    hipMemsetAsync(d_out, 0, (size_t)out_size * 4, stream);
    return;
  }
  int nchunks = (Nd + Nc - 1) / Nc;
  int NcB = (((Nd + nchunks - 1) / nchunks) + 127) / 128 * 128;  // balance chunks
  if (NcB <= Nc) Nc = NcB;
  nchunks = (Nd + Nc - 1) / Nc;

  unsigned short* bt1  = (unsigned short*)(ws + o_bt1);
  unsigned short* bt2  = (unsigned short*)(ws + o_bt2);
  unsigned short* xd16 = (unsigned short*)(ws + o_xd);

  char* chunk_base = ws + fixed_end;
  int*   cnt_c  = (int*)chunk_base;                                   // Nc*8 ints
  float* sums_c = (float*)(chunk_base + (size_t)Nc * 32);             // Nc*8*1024 B
  unsigned short* agg_c = (unsigned short*)sums_c;                    // bf16 in place
  unsigned short* h_c   = (unsigned short*)(chunk_base + (size_t)Nc * 32 +
                                            (size_t)Nc * 8192);       // Nc*512 B

  // ---- fixed prep ----
  k_build_bt<<<(D_DIM * 2304 + 255) / 256, 256, 0, stream>>>(w1, root1, bt1);
  k_build_bt<<<(D_DIM * 2304 + 255) / 256, 256, 0, stream>>>(w2, root2, bt2);
  k_cvt_bf16<<<(Nd * 64 + 255) / 256, 256, 0, stream>>>(x_dst, xd16, Nd * 64);

  // ---- chunk loop ----
  for (int c = 0; c < nchunks; ++c) {
    int n0 = c * Nc;
    int Mc = Nd - n0 < Nc ? Nd - n0 : Nc;
    hipMemsetAsync(chunk_base, 0, (size_t)Nc * 32 + (size_t)Mc * 8192, stream);
    k_aggregate<<<2048, 256, 0, stream>>>(x_src, srcI, dstI, etype, n0, n0 + Mc,
                                          sums_c, cnt_c, E);
    k_finalize<<<(Mc * 8 + 3) / 4, 256, 0, stream>>>(sums_c, cnt_c, Mc * 8);
    int mb = (Mc + 127) / 128;
    k_gemm<1><<<mb * 2, 256, 0, stream>>>(agg_c, xd16 + (size_t)n0 * D_DIM, bt1, b1,
                                          (void*)h_c, Mc);
    k_gemm<0><<<mb * 2, 256, 0, stream>>>(agg_c, h_c, bt2, b2,
                                          (void*)((float*)d_out + (size_t)n0 * D_DIM), Mc);
  }
}

// Round 5
// 410.287 us; speedup vs baseline: 14.8276x; 3.4885x over previous
//
#include <hip/hip_runtime.h>
#include <hip/hip_bf16.h>

#define D_DIM 256
#define R_REL 8

typedef __attribute__((ext_vector_type(8))) short short8;
typedef __attribute__((ext_vector_type(4))) float f32x4;

static __device__ __forceinline__ unsigned short f2bf(float f) {
  unsigned u = __float_as_uint(f);
  u += 0x7FFF + ((u >> 16) & 1);   // round-to-nearest-even
  return (unsigned short)(u >> 16);
}

// ---- weight prep -----------------------------------------------------------

// Bt[n][k] = (k < 2048 ? W[k/256][k%256][n] : root[k-2048][n]), bf16, k-contiguous
__global__ void k_build_bt(const float* __restrict__ w, const float* __restrict__ root,
                           unsigned short* __restrict__ bt) {
  const int KT = R_REL * D_DIM + D_DIM;  // 2304
  int idx = blockIdx.x * 256 + threadIdx.x;
  if (idx >= D_DIM * KT) return;
  int n = idx / KT, k = idx - n * KT;
  float v = (k < R_REL * D_DIM) ? w[(size_t)k * D_DIM + n]
                                : root[(size_t)(k - R_REL * D_DIM) * D_DIM + n];
  bt[idx] = f2bf(v);
}

__global__ void k_cvt_bf16(const float* __restrict__ in, unsigned short* __restrict__ out,
                           int n4) {
  int i = blockIdx.x * 256 + threadIdx.x;
  if (i >= n4) return;
  float4 v = ((const float4*)in)[i];
  ushort4 o = { f2bf(v.x), f2bf(v.y), f2bf(v.z), f2bf(v.w) };
  ((ushort4*)out)[i] = o;
}

// ---- per-segment edge lists (lock-free linked list) ------------------------
// head[seg] -> newest edge id, nxt[e] -> older edge with same seg (-1 = end).
// Only atomics in the whole pipeline: one atomicExch per edge on a 1MB array.

__global__ void k_link(const int* __restrict__ dst, const int* __restrict__ et,
                       int* __restrict__ head, int* __restrict__ nxt, int E) {
  int e = blockIdx.x * 256 + threadIdx.x;
  if (e >= E) return;
  int seg = dst[e] * R_REL + et[e];
  nxt[e] = atomicExch(&head[seg], e);
}

// One wave per segment: walk list, register-accumulate 1KB x_src rows, write
// the bf16 MEAN directly (finalize fused; empty segments write zeros).
__global__ void k_gather(const float* __restrict__ xsrc, const int* __restrict__ src,
                         const int* __restrict__ nxt, const int* __restrict__ head,
                         unsigned short* __restrict__ agg, int seg0, int nsegc) {
  int sg = blockIdx.x * 4 + (threadIdx.x >> 6);
  if (sg >= nsegc) return;
  int lane = threadIdx.x & 63;
  int e = head[seg0 + sg];          // wave-uniform
  float4 acc = {0.f, 0.f, 0.f, 0.f};
  int n = 0;
  while (e >= 0) {
    int s = src[e];
    float4 v = ((const float4*)(xsrc + (size_t)s * D_DIM))[lane];
    acc.x += v.x; acc.y += v.y; acc.z += v.z; acc.w += v.w;
    ++n;
    e = nxt[e];
  }
  float inv = (n > 0) ? (1.0f / (float)n) : 0.0f;
  ushort4 o = { f2bf(acc.x * inv), f2bf(acc.y * inv), f2bf(acc.z * inv), f2bf(acc.w * inv) };
  ((ushort4*)(agg + (size_t)sg * 256))[lane] = o;
}

// ---- GEMM ------------------------------------------------------------------
// C(Mc x 256) = [Agg (Mc x 2048 dense bf16) | Aroot (Mc x 256)] @ Bt^T
// (+bias, opt relu). 128x128 tile, BK=64, 4 waves (2x2), 16x16x32 bf16 MFMA.
// LDS [128][64 bf16] XOR-swizzled: 16B-element c16 of row r lives at slot
// (c16 ^ (r&7)); LDS dest stays linear-in-lane (m104), the GLOBAL source is
// inverse-swizzled (m173), ds_read applies the same XOR (rule 21).

__device__ __forceinline__ void gload_lds16(const void* g, void* l) {
  __builtin_amdgcn_global_load_lds(
      (const __attribute__((address_space(1))) void*)g,
      (__attribute__((address_space(3))) void*)l, 16, 0, 0);
}

template <int RELU_BF16>
__global__ __launch_bounds__(256, 2) void k_gemm(
    const unsigned short* __restrict__ Agg,    // Mc x 2048, dense
    const unsigned short* __restrict__ Aroot,  // Mc x 256, dense
    const unsigned short* __restrict__ Bt,     // 256 x 2304
    const float* __restrict__ bias,            // 256
    void* __restrict__ Cout,                   // Mc x 256 (bf16 if RELU_BF16 else f32)
    int M) {
  const int KT = 2304, KA = 2048;
  __shared__ __align__(16) char smA[128 * 128];
  __shared__ __align__(16) char smB[128 * 128];
  int tid = threadIdx.x;
  int bn = blockIdx.x & 1;
  int bm = blockIdx.x >> 1;
  int lane = tid & 63;
  int wv = tid >> 6, wm = wv >> 1, wn = wv & 1;
  int lr = lane & 15, lk = lane >> 4;

  f32x4 acc[4][4] = {};

  int rloc = tid >> 3;     // 0..31 (+ c*32)
  int sslot = tid & 7;     // 16B slot within a 128B LDS row

  for (int step = 0; step < KT / 64; ++step) {
    int k0 = step * 64;
    const unsigned short* Ap;
    int strideA, colA;
    if (k0 < KA) { Ap = Agg;   strideA = 2048; colA = k0; }
    else         { Ap = Aroot; strideA = 256;  colA = k0 - KA; }

    __syncthreads();
#pragma unroll
    for (int c = 0; c < 4; ++c) {
      int r = c * 32 + rloc;
      int c16 = sslot ^ (r & 7);                 // inverse-swizzled source element
      int gr = bm * 128 + r; if (gr >= M) gr = M - 1;
      gload_lds16(Ap + (size_t)gr * strideA + colA + c16 * 8,
                  smA + r * 128 + sslot * 16);
      gload_lds16(Bt + (size_t)(bn * 128 + r) * KT + k0 + c16 * 8,
                  smB + r * 128 + sslot * 16);
    }
    asm volatile("s_waitcnt vmcnt(0)" ::: "memory");
    __syncthreads();

#pragma unroll
    for (int ks = 0; ks < 2; ++ks) {
      short8 af[4], bfr[4];
#pragma unroll
      for (int m = 0; m < 4; ++m) {
        int row = wm * 64 + m * 16 + lr;
        af[m] = *(const short8*)(smA + row * 128 + (((ks * 4 + lk) ^ (row & 7)) << 4));
      }
#pragma unroll
      for (int n = 0; n < 4; ++n) {
        int row = wn * 64 + n * 16 + lr;
        bfr[n] = *(const short8*)(smB + row * 128 + (((ks * 4 + lk) ^ (row & 7)) << 4));
      }
#pragma unroll
      for (int m = 0; m < 4; ++m)
#pragma unroll
        for (int n = 0; n < 4; ++n)
          acc[m][n] = __builtin_amdgcn_mfma_f32_16x16x32_bf16(af[m], bfr[n], acc[m][n], 0, 0, 0);
    }
  }

  // epilogue: C/D layout col=lane&15, row=(lane>>4)*4+reg (m89)
#pragma unroll
  for (int n = 0; n < 4; ++n) {
    int col = bn * 128 + wn * 64 + n * 16 + lr;
    float bv = bias[col];
#pragma unroll
    for (int m = 0; m < 4; ++m) {
#pragma unroll
      for (int j = 0; j < 4; ++j) {
        int row = bm * 128 + wm * 64 + m * 16 + lk * 4 + j;
        if (row < M) {
          float v = acc[m][n][j] + bv;
          if (RELU_BF16) {
            v = fmaxf(v, 0.0f);
            ((unsigned short*)Cout)[(size_t)row * D_DIM + col] = f2bf(v);
          } else {
            ((float*)Cout)[(size_t)row * D_DIM + col] = v;
          }
        }
      }
    }
  }
}

// ---- launch ----------------------------------------------------------------

extern "C" void kernel_launch(void* const* d_in, const int* in_sizes, int n_in,
                              void* d_out, int out_size, void* d_ws, size_t ws_size,
                              hipStream_t stream) {
  const float* x_src = (const float*)d_in[0];
  const float* x_dst = (const float*)d_in[1];
  const int*   eidx  = (const int*)d_in[2];
  const int*   etype = (const int*)d_in[3];
  const float* w1    = (const float*)d_in[4];
  const float* root1 = (const float*)d_in[5];
  const float* b1    = (const float*)d_in[6];
  const float* w2    = (const float*)d_in[7];
  const float* root2 = (const float*)d_in[8];
  const float* b2    = (const float*)d_in[9];

  const int E  = in_sizes[3];
  const int Nd = in_sizes[1] / D_DIM;
  const int nseg = Nd * R_REL;
  const int* srcI = eidx;
  const int* dstI = eidx + E;

  char* ws = (char*)d_ws;
  size_t off = 0;
  auto alloc = [&](size_t bytes) {
    size_t o = off;
    off += (bytes + 255) & ~(size_t)255;
    return o;
  };
  // fixed region
  size_t o_bt1  = alloc((size_t)D_DIM * 2304 * 2);
  size_t o_bt2  = alloc((size_t)D_DIM * 2304 * 2);
  size_t o_xd   = alloc((size_t)Nd * D_DIM * 2);
  size_t o_head = alloc((size_t)nseg * 4);
  size_t o_nxt  = alloc((size_t)E * 4);
  size_t fixed_end = off;

  // adaptive chunk size: per-node = agg bf16 (8*512) + h bf16 (512)
  const size_t per_node = 4096 + 512;
  long long avail = (long long)ws_size - (long long)fixed_end - 4096;
  int Nc = avail > 0 ? (int)(avail / (long long)per_node) : 0;
  if (Nc > Nd) Nc = Nd;
  Nc = (Nc / 128) * 128;
  if (Nc < 128) {  // hopelessly small ws: deterministic zero output (diagnostic)
    hipMemsetAsync(d_out, 0, (size_t)out_size * 4, stream);
    return;
  }
  int nchunks = (Nd + Nc - 1) / Nc;
  int NcB = (((Nd + nchunks - 1) / nchunks) + 127) / 128 * 128;  // balance chunks
  if (NcB <= Nc) Nc = NcB;
  nchunks = (Nd + Nc - 1) / Nc;

  unsigned short* bt1  = (unsigned short*)(ws + o_bt1);
  unsigned short* bt2  = (unsigned short*)(ws + o_bt2);
  unsigned short* xd16 = (unsigned short*)(ws + o_xd);
  int* head = (int*)(ws + o_head);
  int* nxt  = (int*)(ws + o_nxt);

  char* chunk_base = ws + fixed_end;
  unsigned short* agg_c = (unsigned short*)chunk_base;                  // Nc*4096 B
  unsigned short* h_c   = (unsigned short*)(chunk_base + (size_t)Nc * 4096);  // Nc*512 B

  // ---- fixed prep ----
  hipMemsetAsync(head, 0xFF, (size_t)nseg * 4, stream);  // -1
  k_build_bt<<<(D_DIM * 2304 + 255) / 256, 256, 0, stream>>>(w1, root1, bt1);
  k_build_bt<<<(D_DIM * 2304 + 255) / 256, 256, 0, stream>>>(w2, root2, bt2);
  k_cvt_bf16<<<(Nd * 64 + 255) / 256, 256, 0, stream>>>(x_dst, xd16, Nd * 64);
  k_link<<<(E + 255) / 256, 256, 0, stream>>>(dstI, etype, head, nxt, E);

  // ---- chunk loop ----
  for (int c = 0; c < nchunks; ++c) {
    int n0 = c * Nc;
    int Mc = Nd - n0 < Nc ? Nd - n0 : Nc;
    int nsegc = Mc * R_REL;
    k_gather<<<(nsegc + 3) / 4, 256, 0, stream>>>(x_src, srcI, nxt, head,
                                                  agg_c, n0 * R_REL, nsegc);
    int mb = (Mc + 127) / 128;
    k_gemm<1><<<mb * 2, 256, 0, stream>>>(agg_c, xd16 + (size_t)n0 * D_DIM, bt1, b1,
                                          (void*)h_c, Mc);
    k_gemm<0><<<mb * 2, 256, 0, stream>>>(agg_c, h_c, bt2, b2,
                                          (void*)((float*)d_out + (size_t)n0 * D_DIM), Mc);
  }
}

// Round 6
// 368.993 us; speedup vs baseline: 16.4869x; 1.1119x over previous
//
#include <hip/hip_runtime.h>
#include <hip/hip_bf16.h>

#define D_DIM 256
#define R_REL 8
#define KT 2304

typedef __attribute__((ext_vector_type(8))) short short8;
typedef __attribute__((ext_vector_type(4))) float f32x4;

static __device__ __forceinline__ unsigned short f2bf(float f) {
  unsigned u = __float_as_uint(f);
  u += 0x7FFF + ((u >> 16) & 1);   // round-to-nearest-even
  return (unsigned short)(u >> 16);
}

// ---- weight prep -----------------------------------------------------------

// Bt[n][k] = (k < 2048 ? W[k/256][k%256][n] : root[k-2048][n]), bf16, k-contiguous
__global__ void k_build_bt(const float* __restrict__ w, const float* __restrict__ root,
                           unsigned short* __restrict__ bt) {
  int idx = blockIdx.x * 256 + threadIdx.x;
  if (idx >= D_DIM * KT) return;
  int n = idx / KT, k = idx - n * KT;
  float v = (k < R_REL * D_DIM) ? w[(size_t)k * D_DIM + n]
                                : root[(size_t)(k - R_REL * D_DIM) * D_DIM + n];
  bt[idx] = f2bf(v);
}

__global__ void k_cvt_bf16(const float* __restrict__ in, unsigned short* __restrict__ out,
                           int n4) {
  int i = blockIdx.x * 256 + threadIdx.x;
  if (i >= n4) return;
  float4 v = ((const float4*)in)[i];
  ushort4 o = { f2bf(v.x), f2bf(v.y), f2bf(v.z), f2bf(v.w) };
  ((ushort4*)out)[i] = o;
}

// ---- per-segment edge lists (lock-free linked list) ------------------------

__global__ void k_link(const int* __restrict__ dst, const int* __restrict__ et,
                       int* __restrict__ head, int* __restrict__ nxt, int E) {
  int e = blockIdx.x * 256 + threadIdx.x;
  if (e >= E) return;
  int seg = dst[e] * R_REL + et[e];
  nxt[e] = atomicExch(&head[seg], e);
}

// One wave per segment: walk list, register-accumulate 1KB x_src rows, write
// the bf16 MEAN directly (empty segments write zeros).
__global__ void k_gather(const float* __restrict__ xsrc, const int* __restrict__ src,
                         const int* __restrict__ nxt, const int* __restrict__ head,
                         unsigned short* __restrict__ agg, int seg0, int nsegc) {
  int sg = blockIdx.x * 4 + (threadIdx.x >> 6);
  if (sg >= nsegc) return;
  int lane = threadIdx.x & 63;
  int e = head[seg0 + sg];          // wave-uniform
  float4 acc = {0.f, 0.f, 0.f, 0.f};
  int n = 0;
  while (e >= 0) {
    int s = src[e];
    float4 v = ((const float4*)(xsrc + (size_t)s * D_DIM))[lane];
    acc.x += v.x; acc.y += v.y; acc.z += v.z; acc.w += v.w;
    ++n;
    e = nxt[e];
  }
  float inv = (n > 0) ? (1.0f / (float)n) : 0.0f;
  ushort4 o = { f2bf(acc.x * inv), f2bf(acc.y * inv), f2bf(acc.z * inv), f2bf(acc.w * inv) };
  ((ushort4*)(agg + (size_t)sg * 256))[lane] = o;
}

// ---- fused two-layer GEMM --------------------------------------------------
// Block: BM=128 rows, BN=256 (all cols), BK=32, 8 waves (2m x 4n).
// Layer1: h = relu([agg|xd] @ Bt1^T + b1)  (h kept in LDS, bf16)
// Layer2: out = [agg|h] @ Bt2^T + b2       (agg staged ONCE for both layers)
// LDS 144KB dynamic: A 2x8K | B1 2x16K | B2 2x16K | H 64K.
// 64B-row tiles swizzle 16B-slot: slot ^ ((row>>1)&3); H (512B rows):
// byte ^ ((row&7)<<4). gload_lds dest linear-in-thread (m104); global source
// inverse-swizzled (m173); ds_read applies the same XOR (rule 21).

__device__ __forceinline__ void gload_lds16(const void* g, void* l) {
  __builtin_amdgcn_global_load_lds(
      (const __attribute__((address_space(1))) void*)g,
      (__attribute__((address_space(3))) void*)l, 16, 0, 0);
}

__global__ __launch_bounds__(512, 2) void k_fused(
    const unsigned short* __restrict__ Agg,   // M x 2048
    const unsigned short* __restrict__ Xd,    // M x 256
    const unsigned short* __restrict__ Bt1,   // 256 x 2304
    const unsigned short* __restrict__ Bt2,   // 256 x 2304
    const float* __restrict__ b1,
    const float* __restrict__ b2,
    float* __restrict__ Out,                  // M x 256 f32
    int M) {
  extern __shared__ __align__(16) char lds[];
  char* smA  = lds;              // [2][128*64]
  char* smB1 = lds + 16 * 1024;  // [2][256*64]
  char* smB2 = lds + 48 * 1024;  // [2][256*64]
  char* smH  = lds + 80 * 1024;  // [128][512]

  int tid = threadIdx.x;
  int bm = blockIdx.x;
  int lane = tid & 63;
  int wid = tid >> 6;
  int wm = wid >> 2, wn = wid & 3;
  int lr = lane & 15, lk = lane >> 4;

  f32x4 acc1[4][4] = {};
  f32x4 acc2[4][4] = {};

  int arow = tid >> 2, aslot = tid & 3;

  auto stageA = [&](int buf, int step) {
    const unsigned short* Ap; int strideA, colA;
    if (step < 64) { Ap = Agg; strideA = 2048; colA = step * 32; }
    else           { Ap = Xd;  strideA = 256;  colA = (step - 64) * 32; }
    int gr = bm * 128 + arow; if (gr >= M) gr = M - 1;
    int srcslot = aslot ^ ((arow >> 1) & 3);
    gload_lds16(Ap + (size_t)gr * strideA + colA + srcslot * 8,
                smA + buf * 8192 + tid * 16);
  };
  auto stageB = [&](char* smB, int buf, const unsigned short* Bt, int kcol) {
#pragma unroll
    for (int i = 0; i < 2; ++i) {
      int u = i * 512 + tid;
      int row = u >> 2, slot = u & 3;
      int srcslot = slot ^ ((row >> 1) & 3);
      gload_lds16(Bt + (size_t)row * KT + kcol + srcslot * 8,
                  smB + buf * 16384 + u * 16);
    }
  };

  // prologue
  stageA(0, 0); stageB(smB1, 0, Bt1, 0); stageB(smB2, 0, Bt2, 0);
  asm volatile("s_waitcnt vmcnt(0)" ::: "memory");
  __syncthreads();

  int buf = 0;
  // ---- 64 dual-layer steps over agg-K ----
  for (int t = 0; t < 64; ++t) {
    stageA(buf ^ 1, t + 1);
    stageB(smB1, buf ^ 1, Bt1, (t + 1) * 32);
    if (t + 1 < 64) stageB(smB2, buf ^ 1, Bt2, (t + 1) * 32);
    short8 af[4], bfr1[4], bfr2[4];
#pragma unroll
    for (int m = 0; m < 4; ++m) {
      int row = wm * 64 + m * 16 + lr;
      af[m] = *(const short8*)(smA + buf * 8192 + row * 64 + ((lk ^ ((row >> 1) & 3)) << 4));
    }
#pragma unroll
    for (int n = 0; n < 4; ++n) {
      int row = wn * 64 + n * 16 + lr;
      int off = row * 64 + ((lk ^ ((row >> 1) & 3)) << 4);
      bfr1[n] = *(const short8*)(smB1 + buf * 16384 + off);
      bfr2[n] = *(const short8*)(smB2 + buf * 16384 + off);
    }
#pragma unroll
    for (int m = 0; m < 4; ++m)
#pragma unroll
      for (int n = 0; n < 4; ++n) {
        acc1[m][n] = __builtin_amdgcn_mfma_f32_16x16x32_bf16(af[m], bfr1[n], acc1[m][n], 0, 0, 0);
        acc2[m][n] = __builtin_amdgcn_mfma_f32_16x16x32_bf16(af[m], bfr2[n], acc2[m][n], 0, 0, 0);
      }
    asm volatile("s_waitcnt vmcnt(0)" ::: "memory");
    __syncthreads();
    buf ^= 1;
  }

  // ---- 8 layer1-only steps over xd @ root1 ----
  for (int t = 64; t < 72; ++t) {
    if (t < 71) {
      stageA(buf ^ 1, t + 1);
      stageB(smB1, buf ^ 1, Bt1, (t + 1) * 32);
    }
    short8 af[4], bfr1[4];
#pragma unroll
    for (int m = 0; m < 4; ++m) {
      int row = wm * 64 + m * 16 + lr;
      af[m] = *(const short8*)(smA + buf * 8192 + row * 64 + ((lk ^ ((row >> 1) & 3)) << 4));
    }
#pragma unroll
    for (int n = 0; n < 4; ++n) {
      int row = wn * 64 + n * 16 + lr;
      bfr1[n] = *(const short8*)(smB1 + buf * 16384 + row * 64 + ((lk ^ ((row >> 1) & 3)) << 4));
    }
#pragma unroll
    for (int m = 0; m < 4; ++m)
#pragma unroll
      for (int n = 0; n < 4; ++n)
        acc1[m][n] = __builtin_amdgcn_mfma_f32_16x16x32_bf16(af[m], bfr1[n], acc1[m][n], 0, 0, 0);
    asm volatile("s_waitcnt vmcnt(0)" ::: "memory");
    __syncthreads();
    buf ^= 1;
  }

  // ---- h = relu(acc1 + b1) -> LDS bf16 (swizzled) ----
  float b1v[4];
#pragma unroll
  for (int n = 0; n < 4; ++n) b1v[n] = b1[wn * 64 + n * 16 + lr];
#pragma unroll
  for (int m = 0; m < 4; ++m)
#pragma unroll
    for (int n = 0; n < 4; ++n)
#pragma unroll
      for (int j = 0; j < 4; ++j) {
        int row = wm * 64 + m * 16 + lk * 4 + j;
        int col = wn * 64 + n * 16 + lr;
        float v = fmaxf(acc1[m][n][j] + b1v[n], 0.0f);
        *(unsigned short*)(smH + row * 512 + ((col * 2) ^ ((row & 7) << 4))) = f2bf(v);
      }
  __syncthreads();

  // ---- 8 layer2 steps over h @ root2 ----
  stageB(smB2, 0, Bt2, 2048);
  asm volatile("s_waitcnt vmcnt(0)" ::: "memory");
  __syncthreads();
  for (int s = 0; s < 8; ++s) {
    if (s < 7) stageB(smB2, (s + 1) & 1, Bt2, 2048 + (s + 1) * 32);
    short8 ah[4], bfr2[4];
#pragma unroll
    for (int m = 0; m < 4; ++m) {
      int row = wm * 64 + m * 16 + lr;
      ah[m] = *(const short8*)(smH + row * 512 + ((s * 64 + lk * 16) ^ ((row & 7) << 4)));
    }
#pragma unroll
    for (int n = 0; n < 4; ++n) {
      int row = wn * 64 + n * 16 + lr;
      bfr2[n] = *(const short8*)(smB2 + (s & 1) * 16384 + row * 64 + ((lk ^ ((row >> 1) & 3)) << 4));
    }
#pragma unroll
    for (int m = 0; m < 4; ++m)
#pragma unroll
      for (int n = 0; n < 4; ++n)
        acc2[m][n] = __builtin_amdgcn_mfma_f32_16x16x32_bf16(ah[m], bfr2[n], acc2[m][n], 0, 0, 0);
    asm volatile("s_waitcnt vmcnt(0)" ::: "memory");
    __syncthreads();
  }

  // ---- epilogue: out = acc2 + b2 (f32) ----
  float b2v[4];
#pragma unroll
  for (int n = 0; n < 4; ++n) b2v[n] = b2[wn * 64 + n * 16 + lr];
#pragma unroll
  for (int m = 0; m < 4; ++m)
#pragma unroll
    for (int n = 0; n < 4; ++n)
#pragma unroll
      for (int j = 0; j < 4; ++j) {
        int row = bm * 128 + wm * 64 + m * 16 + lk * 4 + j;
        if (row < M)
          Out[(size_t)row * D_DIM + wn * 64 + n * 16 + lr] = acc2[m][n][j] + b2v[n];
      }
}

// ---- launch ----------------------------------------------------------------

extern "C" void kernel_launch(void* const* d_in, const int* in_sizes, int n_in,
                              void* d_out, int out_size, void* d_ws, size_t ws_size,
                              hipStream_t stream) {
  const float* x_src = (const float*)d_in[0];
  const float* x_dst = (const float*)d_in[1];
  const int*   eidx  = (const int*)d_in[2];
  const int*   etype = (const int*)d_in[3];
  const float* w1    = (const float*)d_in[4];
  const float* root1 = (const float*)d_in[5];
  const float* b1    = (const float*)d_in[6];
  const float* w2    = (const float*)d_in[7];
  const float* root2 = (const float*)d_in[8];
  const float* b2    = (const float*)d_in[9];

  const int E  = in_sizes[3];
  const int Nd = in_sizes[1] / D_DIM;
  const int nseg = Nd * R_REL;
  const int* srcI = eidx;
  const int* dstI = eidx + E;

  char* ws = (char*)d_ws;
  size_t off = 0;
  auto alloc = [&](size_t bytes) {
    size_t o = off;
    off += (bytes + 255) & ~(size_t)255;
    return o;
  };
  size_t o_bt1  = alloc((size_t)D_DIM * KT * 2);
  size_t o_bt2  = alloc((size_t)D_DIM * KT * 2);
  size_t o_xd   = alloc((size_t)Nd * D_DIM * 2);
  size_t o_head = alloc((size_t)nseg * 4);
  size_t o_nxt  = alloc((size_t)E * 4);
  size_t fixed_end = off;

  // adaptive chunk size: per-node = agg bf16 (8*512 B)
  const size_t per_node = 4096;
  long long avail = (long long)ws_size - (long long)fixed_end - 4096;
  int Nc = avail > 0 ? (int)(avail / (long long)per_node) : 0;
  if (Nc > Nd) Nc = Nd;
  Nc = (Nc / 128) * 128;
  if (Nc < 128) {
    hipMemsetAsync(d_out, 0, (size_t)out_size * 4, stream);
    return;
  }
  int nchunks = (Nd + Nc - 1) / Nc;
  int NcB = (((Nd + nchunks - 1) / nchunks) + 127) / 128 * 128;
  if (NcB <= Nc) Nc = NcB;
  nchunks = (Nd + Nc - 1) / Nc;

  unsigned short* bt1  = (unsigned short*)(ws + o_bt1);
  unsigned short* bt2  = (unsigned short*)(ws + o_bt2);
  unsigned short* xd16 = (unsigned short*)(ws + o_xd);
  int* head = (int*)(ws + o_head);
  int* nxt  = (int*)(ws + o_nxt);
  unsigned short* agg_c = (unsigned short*)(ws + fixed_end);   // Nc*4096 B

  const int LDS_BYTES = 144 * 1024;
  hipFuncSetAttribute((const void*)k_fused,
                      hipFuncAttributeMaxDynamicSharedMemorySize, LDS_BYTES);

  // ---- fixed prep ----
  hipMemsetAsync(head, 0xFF, (size_t)nseg * 4, stream);  // -1
  k_build_bt<<<(D_DIM * KT + 255) / 256, 256, 0, stream>>>(w1, root1, bt1);
  k_build_bt<<<(D_DIM * KT + 255) / 256, 256, 0, stream>>>(w2, root2, bt2);
  k_cvt_bf16<<<(Nd * 64 + 255) / 256, 256, 0, stream>>>(x_dst, xd16, Nd * 64);
  k_link<<<(E + 255) / 256, 256, 0, stream>>>(dstI, etype, head, nxt, E);

  // ---- chunk loop ----
  for (int c = 0; c < nchunks; ++c) {
    int n0 = c * Nc;
    int Mc = Nd - n0 < Nc ? Nd - n0 : Nc;
    int nsegc = Mc * R_REL;
    k_gather<<<(nsegc + 3) / 4, 256, 0, stream>>>(x_src, srcI, nxt, head,
                                                  agg_c, n0 * R_REL, nsegc);
    int mb = (Mc + 127) / 128;
    k_fused<<<mb, 512, LDS_BYTES, stream>>>(agg_c, xd16 + (size_t)n0 * D_DIM,
                                            bt1, bt2, b1, b2,
                                            (float*)d_out + (size_t)n0 * D_DIM, Mc);
  }
}

// Round 7
// 303.408 us; speedup vs baseline: 20.0508x; 1.2162x over previous
//
#include <hip/hip_runtime.h>
#include <hip/hip_bf16.h>

#define D_DIM 256
#define R_REL 8
#define KT 2304

typedef __attribute__((ext_vector_type(8))) short short8;
typedef __attribute__((ext_vector_type(4))) float f32x4;

#define WAITCNT_VM(N) asm volatile("s_waitcnt vmcnt(" #N ")" ::: "memory")

static __device__ __forceinline__ unsigned short f2bf(float f) {
  unsigned u = __float_as_uint(f);
  u += 0x7FFF + ((u >> 16) & 1);   // round-to-nearest-even
  return (unsigned short)(u >> 16);
}

// ---- weight prep -----------------------------------------------------------

// Bt[n][k] = (k < 2048 ? W[k/256][k%256][n] : root[k-2048][n]), bf16, k-contiguous
__global__ void k_build_bt(const float* __restrict__ w, const float* __restrict__ root,
                           unsigned short* __restrict__ bt) {
  int idx = blockIdx.x * 256 + threadIdx.x;
  if (idx >= D_DIM * KT) return;
  int n = idx / KT, k = idx - n * KT;
  float v = (k < R_REL * D_DIM) ? w[(size_t)k * D_DIM + n]
                                : root[(size_t)(k - R_REL * D_DIM) * D_DIM + n];
  bt[idx] = f2bf(v);
}

__global__ void k_cvt_bf16(const float* __restrict__ in, unsigned short* __restrict__ out,
                           int n4) {
  int i = blockIdx.x * 256 + threadIdx.x;
  if (i >= n4) return;
  float4 v = ((const float4*)in)[i];
  ushort4 o = { f2bf(v.x), f2bf(v.y), f2bf(v.z), f2bf(v.w) };
  ((ushort4*)out)[i] = o;
}

// ---- per-segment edge lists (lock-free linked list) ------------------------

__global__ void k_link(const int* __restrict__ dst, const int* __restrict__ et,
                       int* __restrict__ head, int* __restrict__ nxt, int E) {
  int e = blockIdx.x * 256 + threadIdx.x;
  if (e >= E) return;
  int seg = dst[e] * R_REL + et[e];
  nxt[e] = atomicExch(&head[seg], e);
}

// One wave per segment: walk list, register-accumulate 1KB x_src rows, write
// the bf16 MEAN directly (empty segments write zeros).
__global__ void k_gather(const float* __restrict__ xsrc, const int* __restrict__ src,
                         const int* __restrict__ nxt, const int* __restrict__ head,
                         unsigned short* __restrict__ agg, int seg0, int nsegc) {
  int sg = blockIdx.x * 16 + (threadIdx.x >> 6);
  if (sg >= nsegc) return;
  int lane = threadIdx.x & 63;
  int e = head[seg0 + sg];          // wave-uniform
  float4 acc = {0.f, 0.f, 0.f, 0.f};
  int n = 0;
  while (e >= 0) {
    int s = src[e];
    float4 v = ((const float4*)(xsrc + (size_t)s * D_DIM))[lane];
    acc.x += v.x; acc.y += v.y; acc.z += v.z; acc.w += v.w;
    ++n;
    e = nxt[e];
  }
  float inv = (n > 0) ? (1.0f / (float)n) : 0.0f;
  ushort4 o = { f2bf(acc.x * inv), f2bf(acc.y * inv), f2bf(acc.z * inv), f2bf(acc.w * inv) };
  ((ushort4*)(agg + (size_t)sg * 256))[lane] = o;
}

// ---- fused two-layer GEMM --------------------------------------------------
// Block: BM=128 rows, BN=256 (all cols), BK=32, 8 waves (2m x 4n).
// Layer1: h = relu([agg|xd] @ Bt1^T + b1)  (h kept in LDS, bf16)
// Layer2: out = [agg|h] @ Bt2^T + b2       (agg staged ONCE for both layers)
//
// LDS 144KB: 3 staging SETS of 40KB {A 8K | B1 16K | B2 16K} at 0/40K/80K,
// H[128][512B] at 80K..144K (overlaps set2 ONLY after its last read, barrier-
// ordered). Pipeline: stage(t+2) issued at step t; s_waitcnt vmcnt(5/3)
// (counted, never 0 in steady state — T4) + raw s_barrier per step.
// 64B-row tiles swizzle 16B-slot: slot ^ ((row>>1)&3); H rows: byte ^
// ((row&7)<<4). gload_lds dest linear-in-thread (m104); global source
// inverse-swizzled (m173); ds_read applies the same XOR (rule 21).

__device__ __forceinline__ void gload_lds16(const void* g, void* l) {
  __builtin_amdgcn_global_load_lds(
      (const __attribute__((address_space(1))) void*)g,
      (__attribute__((address_space(3))) void*)l, 16, 0, 0);
}

__global__ __launch_bounds__(512, 2) void k_fused(
    const unsigned short* __restrict__ Agg,   // M x 2048
    const unsigned short* __restrict__ Xd,    // M x 256
    const unsigned short* __restrict__ Bt1,   // 256 x 2304
    const unsigned short* __restrict__ Bt2,   // 256 x 2304
    const float* __restrict__ b1,
    const float* __restrict__ b2,
    float* __restrict__ Out,                  // M x 256 f32
    int M) {
  extern __shared__ __align__(16) char lds[];
  char* smH = lds + 80 * 1024;   // [128][512]

  int tid = threadIdx.x;
  int bm = blockIdx.x;
  int lane = tid & 63;
  int wid = tid >> 6;
  int wm = wid >> 2, wn = wid & 3;
  int lr = lane & 15, lk = lane >> 4;

  f32x4 acc1[4][4] = {};
  f32x4 acc2[4][4] = {};

  int arow = tid >> 2, aslot = tid & 3;
  int gr = bm * 128 + arow; if (gr >= M) gr = M - 1;

  // ---- staging helpers (set = 0/1/2 at 40KB stride) ----
  auto stageA = [&](int set, int step) {
    const unsigned short* Ap; int strideA, colA;
    if (step < 64) { Ap = Agg; strideA = 2048; colA = step * 32; }
    else           { Ap = Xd;  strideA = 256;  colA = (step - 64) * 32; }
    int srcslot = aslot ^ ((arow >> 1) & 3);
    gload_lds16(Ap + (size_t)gr * strideA + colA + srcslot * 8,
                lds + set * 40960 + tid * 16);
  };
  auto stageB = [&](int set, int bsel /*0=B1,1=B2*/, int kcol) {
    const unsigned short* Bt = bsel ? Bt2 : Bt1;
#pragma unroll
    for (int i = 0; i < 2; ++i) {
      int u = i * 512 + tid;
      int row = u >> 2, slot = u & 3;
      int srcslot = slot ^ ((row >> 1) & 3);
      gload_lds16(Bt + (size_t)row * KT + kcol + srcslot * 8,
                  lds + set * 40960 + 8192 + bsel * 16384 + u * 16);
    }
  };
  auto stage_full = [&](int set, int step) {   // 5 gload_lds
    stageA(set, step);
    stageB(set, 0, step * 32);
    stageB(set, 1, step * 32);
  };
  auto stage_tail = [&](int set, int step) {   // 3 gload_lds (no B2)
    stageA(set, step);
    stageB(set, 0, step * 32);
  };
  auto stageB2L2 = [&](int half, int kcol) {   // 2 gload_lds, into 0..32K
#pragma unroll
    for (int i = 0; i < 2; ++i) {
      int u = i * 512 + tid;
      int row = u >> 2, slot = u & 3;
      int srcslot = slot ^ ((row >> 1) & 3);
      gload_lds16(Bt2 + (size_t)row * KT + kcol + srcslot * 8,
                  lds + half * 16384 + u * 16);
    }
  };

  // ---- compute helpers ----
  auto loadA = [&](int set, short8* af) {
#pragma unroll
    for (int m = 0; m < 4; ++m) {
      int row = wm * 64 + m * 16 + lr;
      af[m] = *(const short8*)(lds + set * 40960 + row * 64 +
                               ((lk ^ ((row >> 1) & 3)) << 4));
    }
  };
  auto loadB = [&](int set, int bsel, short8* bf) {
#pragma unroll
    for (int n = 0; n < 4; ++n) {
      int row = wn * 64 + n * 16 + lr;
      bf[n] = *(const short8*)(lds + set * 40960 + 8192 + bsel * 16384 +
                               row * 64 + ((lk ^ ((row >> 1) & 3)) << 4));
    }
  };

  // ---- prologue: 2 stages in flight ----
  stage_full(0, 0);
  stage_full(1, 1);
  WAITCNT_VM(5);
  __builtin_amdgcn_s_barrier();

  // ---- steps 0..61: dual-layer, full stage 2 ahead ----
  for (int t = 0; t < 62; ++t) {
    stage_full((t + 2) % 3, t + 2);
    int set = t % 3;
    short8 af[4], bf1[4], bf2[4];
    loadA(set, af); loadB(set, 0, bf1); loadB(set, 1, bf2);
#pragma unroll
    for (int m = 0; m < 4; ++m)
#pragma unroll
      for (int n = 0; n < 4; ++n) {
        acc1[m][n] = __builtin_amdgcn_mfma_f32_16x16x32_bf16(af[m], bf1[n], acc1[m][n], 0, 0, 0);
        acc2[m][n] = __builtin_amdgcn_mfma_f32_16x16x32_bf16(af[m], bf2[n], acc2[m][n], 0, 0, 0);
      }
    WAITCNT_VM(5);
    __builtin_amdgcn_s_barrier();
  }
  // ---- steps 62..63: dual-layer, tail stages ahead ----
  for (int t = 62; t < 64; ++t) {
    stage_tail((t + 2) % 3, t + 2);
    int set = t % 3;
    short8 af[4], bf1[4], bf2[4];
    loadA(set, af); loadB(set, 0, bf1); loadB(set, 1, bf2);
#pragma unroll
    for (int m = 0; m < 4; ++m)
#pragma unroll
      for (int n = 0; n < 4; ++n) {
        acc1[m][n] = __builtin_amdgcn_mfma_f32_16x16x32_bf16(af[m], bf1[n], acc1[m][n], 0, 0, 0);
        acc2[m][n] = __builtin_amdgcn_mfma_f32_16x16x32_bf16(af[m], bf2[n], acc2[m][n], 0, 0, 0);
      }
    WAITCNT_VM(3);
    __builtin_amdgcn_s_barrier();
  }
  // ---- steps 64..69: layer1-only (xd @ root1), tail stages ahead ----
  for (int t = 64; t < 70; ++t) {
    stage_tail((t + 2) % 3, t + 2);
    int set = t % 3;
    short8 af[4], bf1[4];
    loadA(set, af); loadB(set, 0, bf1);
#pragma unroll
    for (int m = 0; m < 4; ++m)
#pragma unroll
      for (int n = 0; n < 4; ++n)
        acc1[m][n] = __builtin_amdgcn_mfma_f32_16x16x32_bf16(af[m], bf1[n], acc1[m][n], 0, 0, 0);
    WAITCNT_VM(3);
    __builtin_amdgcn_s_barrier();
  }
  // ---- steps 70..71: no more staging ----
  for (int t = 70; t < 72; ++t) {
    int set = t % 3;
    short8 af[4], bf1[4];
    loadA(set, af); loadB(set, 0, bf1);
#pragma unroll
    for (int m = 0; m < 4; ++m)
#pragma unroll
      for (int n = 0; n < 4; ++n)
        acc1[m][n] = __builtin_amdgcn_mfma_f32_16x16x32_bf16(af[m], bf1[n], acc1[m][n], 0, 0, 0);
    WAITCNT_VM(0);
    __builtin_amdgcn_s_barrier();
  }

  // ---- h = relu(acc1 + b1) -> LDS bf16 (swizzled); overlap first L2 stage --
  stageB2L2(0, 2048);
  float b1v[4];
#pragma unroll
  for (int n = 0; n < 4; ++n) b1v[n] = b1[wn * 64 + n * 16 + lr];
#pragma unroll
  for (int m = 0; m < 4; ++m)
#pragma unroll
    for (int n = 0; n < 4; ++n)
#pragma unroll
      for (int j = 0; j < 4; ++j) {
        int row = wm * 64 + m * 16 + lk * 4 + j;
        int col = wn * 64 + n * 16 + lr;
        float v = fmaxf(acc1[m][n][j] + b1v[n], 0.0f);
        *(unsigned short*)(smH + row * 512 + ((col * 2) ^ ((row & 7) << 4))) = f2bf(v);
      }
  asm volatile("s_waitcnt vmcnt(0) lgkmcnt(0)" ::: "memory");
  __builtin_amdgcn_s_barrier();

  // ---- 8 layer2 steps over h @ root2 (B2 dbuf in 0..32K) ----
  for (int s = 0; s < 8; ++s) {
    if (s < 7) stageB2L2((s + 1) & 1, 2048 + (s + 1) * 32);
    short8 ah[4], bf2[4];
#pragma unroll
    for (int m = 0; m < 4; ++m) {
      int row = wm * 64 + m * 16 + lr;
      ah[m] = *(const short8*)(smH + row * 512 + ((s * 64 + lk * 16) ^ ((row & 7) << 4)));
    }
#pragma unroll
    for (int n = 0; n < 4; ++n) {
      int row = wn * 64 + n * 16 + lr;
      bf2[n] = *(const short8*)(lds + ((s & 1) * 16384) + row * 64 +
                                ((lk ^ ((row >> 1) & 3)) << 4));
    }
#pragma unroll
    for (int m = 0; m < 4; ++m)
#pragma unroll
      for (int n = 0; n < 4; ++n)
        acc2[m][n] = __builtin_amdgcn_mfma_f32_16x16x32_bf16(ah[m], bf2[n], acc2[m][n], 0, 0, 0);
    WAITCNT_VM(0);
    __builtin_amdgcn_s_barrier();
  }

  // ---- epilogue: out = acc2 + b2 (f32) ----
  float b2v[4];
#pragma unroll
  for (int n = 0; n < 4; ++n) b2v[n] = b2[wn * 64 + n * 16 + lr];
#pragma unroll
  for (int m = 0; m < 4; ++m)
#pragma unroll
    for (int n = 0; n < 4; ++n)
#pragma unroll
      for (int j = 0; j < 4; ++j) {
        int row = bm * 128 + wm * 64 + m * 16 + lk * 4 + j;
        if (row < M)
          Out[(size_t)row * D_DIM + wn * 64 + n * 16 + lr] = acc2[m][n][j] + b2v[n];
      }
}

// ---- launch ----------------------------------------------------------------

extern "C" void kernel_launch(void* const* d_in, const int* in_sizes, int n_in,
                              void* d_out, int out_size, void* d_ws, size_t ws_size,
                              hipStream_t stream) {
  const float* x_src = (const float*)d_in[0];
  const float* x_dst = (const float*)d_in[1];
  const int*   eidx  = (const int*)d_in[2];
  const int*   etype = (const int*)d_in[3];
  const float* w1    = (const float*)d_in[4];
  const float* root1 = (const float*)d_in[5];
  const float* b1    = (const float*)d_in[6];
  const float* w2    = (const float*)d_in[7];
  const float* root2 = (const float*)d_in[8];
  const float* b2    = (const float*)d_in[9];

  const int E  = in_sizes[3];
  const int Nd = in_sizes[1] / D_DIM;
  const int nseg = Nd * R_REL;
  const int* srcI = eidx;
  const int* dstI = eidx + E;

  char* ws = (char*)d_ws;
  size_t off = 0;
  auto alloc = [&](size_t bytes) {
    size_t o = off;
    off += (bytes + 255) & ~(size_t)255;
    return o;
  };
  size_t o_bt1  = alloc((size_t)D_DIM * KT * 2);
  size_t o_bt2  = alloc((size_t)D_DIM * KT * 2);
  size_t o_xd   = alloc((size_t)Nd * D_DIM * 2);
  size_t o_head = alloc((size_t)nseg * 4);
  size_t o_nxt  = alloc((size_t)E * 4);
  size_t fixed_end = off;

  // chunking only if ws can't hold the full bf16 agg (4096 B/node)
  const size_t per_node = 4096;
  long long avail = (long long)ws_size - (long long)fixed_end - 4096;
  int Nc = avail > 0 ? (int)(avail / (long long)per_node) : 0;
  if (Nc > Nd) Nc = Nd;
  if (Nc < 1) {
    hipMemsetAsync(d_out, 0, (size_t)out_size * 4, stream);
    return;
  }
  int nchunks = (Nd + Nc - 1) / Nc;

  unsigned short* bt1  = (unsigned short*)(ws + o_bt1);
  unsigned short* bt2  = (unsigned short*)(ws + o_bt2);
  unsigned short* xd16 = (unsigned short*)(ws + o_xd);
  int* head = (int*)(ws + o_head);
  int* nxt  = (int*)(ws + o_nxt);
  unsigned short* agg_c = (unsigned short*)(ws + fixed_end);   // Nc*4096 B

  const int LDS_BYTES = 144 * 1024;
  hipFuncSetAttribute((const void*)k_fused,
                      hipFuncAttributeMaxDynamicSharedMemorySize, LDS_BYTES);

  // ---- fixed prep ----
  hipMemsetAsync(head, 0xFF, (size_t)nseg * 4, stream);  // -1
  k_build_bt<<<(D_DIM * KT + 255) / 256, 256, 0, stream>>>(w1, root1, bt1);
  k_build_bt<<<(D_DIM * KT + 255) / 256, 256, 0, stream>>>(w2, root2, bt2);
  k_cvt_bf16<<<(Nd * 64 + 255) / 256, 256, 0, stream>>>(x_dst, xd16, Nd * 64);
  k_link<<<(E + 255) / 256, 256, 0, stream>>>(dstI, etype, head, nxt, E);

  // ---- chunk loop (expected: 1 chunk) ----
  for (int c = 0; c < nchunks; ++c) {
    int n0 = c * Nc;
    int Mc = Nd - n0 < Nc ? Nd - n0 : Nc;
    int nsegc = Mc * R_REL;
    k_gather<<<(nsegc + 15) / 16, 1024, 0, stream>>>(x_src, srcI, nxt, head,
                                                     agg_c, n0 * R_REL, nsegc);
    int mb = (Mc + 127) / 128;
    k_fused<<<mb, 512, LDS_BYTES, stream>>>(agg_c, xd16 + (size_t)n0 * D_DIM,
                                            bt1, bt2, b1, b2,
                                            (float*)d_out + (size_t)n0 * D_DIM, Mc);
  }
}